// Round 1
// baseline (133.855 us; speedup 1.0000x reference)
//
#include <hip/hip_runtime.h>

#define L 512               // lattice side
#define LM (L - 1)          // 511 mask
#define VROW (L / 4)        // 128 vec4 per row
#define VROW_SHIFT 7
#define ROW_SHIFT 9         // log2(L)

__global__ __launch_bounds__(256) void stencil5_kernel(
    const float4* __restrict__ x4,
    const float*  __restrict__ x,
    float4* __restrict__ out4,
    const float* __restrict__ dp,
    const float* __restrict__ v1p,
    const float* __restrict__ v2p,
    const float* __restrict__ bfp,
    int total_vec)
{
    const float d  = *dp;
    const float v1 = *v1p;
    const float v2 = *v2p;
    const float bf = *bfp;
    const float D  = d * d;
    const float cc = 1.0f - 4.0f * D;   // diagonal (stop_gradient irrelevant in fwd)
    const float cr = D - 0.5f * v1;     // coeff for x[col+1]
    const float cl = D + 0.5f * v1;     // coeff for x[col-1]
    const float cu = D - 0.5f * v2;     // coeff for x[row-1]
    const float cd = D + 0.5f * v2;     // coeff for x[row+1]

    const int stride = gridDim.x * blockDim.x;
    for (int idx = blockIdx.x * blockDim.x + threadIdx.x; idx < total_vec; idx += stride) {
        // idx (vec4 units) = s*65536 + r*128 + vcol
        const int vcol    = idx & (VROW - 1);
        const int r       = (idx >> VROW_SHIFT) & LM;
        const int sbase_v = idx & ~((L * VROW) - 1);        // s * 65536

        const int up_v = sbase_v + (((r - 1) & LM) << VROW_SHIFT) + vcol;
        const int dn_v = sbase_v + (((r + 1) & LM) << VROW_SHIFT) + vcol;

        const float4 ctr = x4[idx];
        const float4 up  = x4[up_v];
        const float4 dn  = x4[dn_v];

        const int    c         = vcol << 2;
        const size_t rowbase_e = ((size_t)(sbase_v + (r << VROW_SHIFT))) << 2;
        const float  leftEdge  = x[rowbase_e + (size_t)((c - 1) & LM)];
        const float  rightEdge = x[rowbase_e + (size_t)((c + 4) & LM)];

        float4 o;
        o.x = cc * ctr.x + cr * ctr.y     + cl * leftEdge + cu * up.x + cd * dn.x + bf;
        o.y = cc * ctr.y + cr * ctr.z     + cl * ctr.x    + cu * up.y + cd * dn.y + bf;
        o.z = cc * ctr.z + cr * ctr.w     + cl * ctr.y    + cu * up.z + cd * dn.z + bf;
        o.w = cc * ctr.w + cr * rightEdge + cl * ctr.z    + cu * up.w + cd * dn.w + bf;
        out4[idx] = o;
    }
}

extern "C" void kernel_launch(void* const* d_in, const int* in_sizes, int n_in,
                              void* d_out, int out_size, void* d_ws, size_t ws_size,
                              hipStream_t stream) {
    const float* x   = (const float*)d_in[0];
    const float* dp  = (const float*)d_in[1];
    const float* v1p = (const float*)d_in[2];
    const float* v2p = (const float*)d_in[3];
    const float* bfp = (const float*)d_in[4];
    float* out = (float*)d_out;

    const int total_vec = in_sizes[0] / 4;   // 16,777,216 vec4s
    const int block = 256;
    const int grid  = 4096;                  // grid-stride; 16K waves over 8K slots

    stencil5_kernel<<<grid, block, 0, stream>>>(
        (const float4*)x, x, (float4*)out, dp, v1p, v2p, bfp, total_vec);
}